// Round 1
// baseline (5538.235 us; speedup 1.0000x reference)
//
#include <hip/hip_runtime.h>
#include <math.h>

// Problem constants (compile-time; reference shapes are fixed)
#define NL   6
#define HD   512     // model dim H (== K proj dim)
#define NHD  8       // heads
#define DK   64      // head dim
#define DFFN 1024
#define NB   8       // batch
#define TT   512     // tgt len == src len
#define MROWS (NB*TT)  // 4096

__device__ __forceinline__ float wave_max(float v) {
#pragma unroll
  for (int off = 32; off; off >>= 1) v = fmaxf(v, __shfl_xor(v, off));
  return v;
}
__device__ __forceinline__ float wave_sum(float v) {
#pragma unroll
  for (int off = 32; off; off >>= 1) v += __shfl_xor(v, off);
  return v;
}

// ---------------------------------------------------------------------------
// Embedding + sinusoidal positional encoding
// grid = MROWS, block = 256 (2 elems / thread)
__global__ __launch_bounds__(256)
void embed_pe_kernel(const int* __restrict__ idx, const float* __restrict__ emb,
                     float* __restrict__ x) {
  const int row = blockIdx.x;            // b*TT + t
  const int t = row & (TT - 1);
  const int tok = idx[row];
  const float cdiv = -0.017988946009466842f;  // -ln(10000)/512
#pragma unroll
  for (int e0 = 0; e0 < 2; ++e0) {
    const int e = threadIdx.x + e0 * 256;
    const float div = __expf((float)(e & ~1) * cdiv);
    const float ang = (float)t * div;
    const float pe = (e & 1) ? cosf(ang) : sinf(ang);
    x[(size_t)row * HD + e] = emb[(size_t)tok * HD + e] + pe;
  }
}

// ---------------------------------------------------------------------------
// f32 GEMM: C[M,N] = A[M,K] @ W[K,N] + bias[N]   (optional ReLU)
// block tile 128x64, BK=16, 256 threads, 8x4 per thread.
#define BM 128
#define BN 64
#define BK 16

__global__ __launch_bounds__(256)
void gemm_kernel(const float* __restrict__ A, const float* __restrict__ W,
                 const float* __restrict__ bias, float* __restrict__ C,
                 int M_, int N_, int K_, int relu) {
  __shared__ float As[BK][BM + 4];   // stride 132 floats (528B, 16B-aligned rows)
  __shared__ float Bs[BK][BN + 8];   // stride 72 floats (288B, 16B-aligned rows)

  const int tid = threadIdx.x;
  const int tx = tid & 15;           // 0..15 -> N
  const int ty = tid >> 4;           // 0..15 -> M
  const int m0 = blockIdx.x * BM;
  const int n0 = blockIdx.y * BN;

  float acc[8][4];
#pragma unroll
  for (int i = 0; i < 8; ++i)
#pragma unroll
    for (int j = 0; j < 4; ++j) acc[i][j] = 0.f;

  for (int k0 = 0; k0 < K_; k0 += BK) {
    // stage A (transposed into LDS): 128 rows x 16 k
    {
      const int mr = tid >> 1;
      const int kc = (tid & 1) * 8;
      const float* ap = A + (size_t)(m0 + mr) * K_ + k0 + kc;
      float4 a0 = *(const float4*)(ap);
      float4 a1 = *(const float4*)(ap + 4);
      As[kc + 0][mr] = a0.x; As[kc + 1][mr] = a0.y;
      As[kc + 2][mr] = a0.z; As[kc + 3][mr] = a0.w;
      As[kc + 4][mr] = a1.x; As[kc + 5][mr] = a1.y;
      As[kc + 6][mr] = a1.z; As[kc + 7][mr] = a1.w;
    }
    // stage B: 16 k x 64 n
    {
      const int kr = tid >> 4;
      const int c = (tid & 15) * 4;
      *(float4*)&Bs[kr][c] = *(const float4*)(W + (size_t)(k0 + kr) * N_ + n0 + c);
    }
    __syncthreads();
#pragma unroll
    for (int kk = 0; kk < BK; ++kk) {
      float4 a0 = *(const float4*)&As[kk][ty * 8];
      float4 a1 = *(const float4*)&As[kk][ty * 8 + 4];
      float4 b0 = *(const float4*)&Bs[kk][tx * 4];
      float a[8] = {a0.x, a0.y, a0.z, a0.w, a1.x, a1.y, a1.z, a1.w};
      float b[4] = {b0.x, b0.y, b0.z, b0.w};
#pragma unroll
      for (int i = 0; i < 8; ++i)
#pragma unroll
        for (int j = 0; j < 4; ++j) acc[i][j] += a[i] * b[j];
    }
    __syncthreads();
  }

  float4 bv = *(const float4*)(bias + n0 + tx * 4);
  float bb[4] = {bv.x, bv.y, bv.z, bv.w};
#pragma unroll
  for (int i = 0; i < 8; ++i) {
    float4 o;
    o.x = acc[i][0] + bb[0];
    o.y = acc[i][1] + bb[1];
    o.z = acc[i][2] + bb[2];
    o.w = acc[i][3] + bb[3];
    if (relu) {
      o.x = fmaxf(o.x, 0.f); o.y = fmaxf(o.y, 0.f);
      o.z = fmaxf(o.z, 0.f); o.w = fmaxf(o.w, 0.f);
    }
    *(float4*)(C + (size_t)(m0 + ty * 8 + i) * N_ + n0 + tx * 4) = o;
  }
}

// ---------------------------------------------------------------------------
// Flash-style attention for one (b, head, 64-q-row block).
// q,k,v: [B*512, HD] with head slice at h*64. ctx: same layout.
// causal=1: self-attn (pad-key from idx, plus upper-triangular mask).
// causal=0: cross-attn (key mask from emask bytes; all zero in practice).
// grid = (B*NHD, TT/64), block = 256 (4 waves x 16 rows).
__global__ __launch_bounds__(256)
void attn_kernel(const float* __restrict__ q, const float* __restrict__ k,
                 const float* __restrict__ v, float* __restrict__ ctx,
                 const int* __restrict__ idx, const unsigned char* __restrict__ emask,
                 int causal) {
  __shared__ float qt[64][68];   // [q-row][d]   (272B rows: 16B aligned)
  __shared__ float kt[64][68];   // [key][d]
  __shared__ float vtT[64][68];  // [d][key]  (transposed for PV)
  __shared__ float pl[4][64];    // per-wave P row

  const int bh = blockIdx.x;
  const int b = bh >> 3;         // NHD = 8
  const int h = bh & 7;
  const int qbase = blockIdx.y * 64;
  const int tid = threadIdx.x;
  const int w = tid >> 6;
  const int lane = tid & 63;

  // stage Q rows once
  {
    const int r = tid >> 2;
    const int c0 = (tid & 3) * 16;
    const float* qp = q + (size_t)(b * TT + qbase + r) * HD + h * DK + c0;
#pragma unroll
    for (int j = 0; j < 4; ++j)
      *(float4*)&qt[r][c0 + j * 4] = *(const float4*)(qp + j * 4);
  }

  float m[16], l[16], acc[16];
#pragma unroll
  for (int i = 0; i < 16; ++i) { m[i] = -1e30f; l[i] = 0.f; acc[i] = 0.f; }

  for (int kt0 = 0; kt0 < TT; kt0 += 64) {
    __syncthreads();  // previous tile fully consumed (also covers q staging)
    {
      const int r = tid >> 2;
      const int c0 = (tid & 3) * 16;
      const float* kp = k + (size_t)(b * TT + kt0 + r) * HD + h * DK + c0;
      const float* vp = v + (size_t)(b * TT + kt0 + r) * HD + h * DK + c0;
#pragma unroll
      for (int j = 0; j < 4; ++j) {
        *(float4*)&kt[r][c0 + j * 4] = *(const float4*)(kp + j * 4);
        float4 u = *(const float4*)(vp + j * 4);
        vtT[c0 + j * 4 + 0][r] = u.x;
        vtT[c0 + j * 4 + 1][r] = u.y;
        vtT[c0 + j * 4 + 2][r] = u.z;
        vtT[c0 + j * 4 + 3][r] = u.w;
      }
    }
    __syncthreads();

    const int kg = kt0 + lane;   // this lane's key (global position)
    const bool keymask = causal ? (idx[b * TT + kg] == 0)
                                : (emask[b * TT + kg] != 0);

#pragma unroll 1
    for (int i = 0; i < 16; ++i) {
      const int r = w * 16 + i;
      const int qpos = qbase + r;
      // QK^T: lane <-> key
      float s = 0.f;
      const float4* qr = (const float4*)&qt[r][0];
      const float4* kr = (const float4*)&kt[lane][0];
#pragma unroll
      for (int j = 0; j < 16; ++j) {
        float4 a = qr[j], bb = kr[j];
        s += a.x * bb.x + a.y * bb.y + a.z * bb.z + a.w * bb.w;
      }
      s *= 0.125f;  // 1/sqrt(64)
      if (keymask || (causal && kg > qpos)) s = -1e9f;

      const float sm = wave_max(s);
      const float mn = fmaxf(m[i], sm);
      const float sc = __expf(m[i] - mn);
      const float p = __expf(s - mn);
      const float ps = wave_sum(p);
      m[i] = mn;
      l[i] = l[i] * sc + ps;
      pl[w][lane] = p;             // wave-internal: no barrier needed

      // PV: lane <-> output dim
      float a = acc[i] * sc;
      const float4* pr = (const float4*)&pl[w][0];
      const float4* vr = (const float4*)&vtT[lane][0];
#pragma unroll
      for (int j = 0; j < 16; ++j) {
        float4 pp = pr[j], vv = vr[j];
        a += pp.x * vv.x + pp.y * vv.y + pp.z * vv.z + pp.w * vv.w;
      }
      acc[i] = a;
    }
  }

#pragma unroll
  for (int i = 0; i < 16; ++i) {
    const int qpos = qbase + w * 16 + i;
    ctx[(size_t)(b * TT + qpos) * HD + h * DK + lane] = acc[i] / l[i];
  }
}

// ---------------------------------------------------------------------------
// Fused residual-add + LayerNorm: out = LN(y + res) * g + b
// grid = MROWS, block = 256 (2 elems / thread). out may alias res.
__global__ __launch_bounds__(256)
void ln_kernel(const float* __restrict__ y, const float* __restrict__ res,
               float* __restrict__ out, const float* __restrict__ g,
               const float* __restrict__ bta) {
  const int row = blockIdx.x;
  const int tid = threadIdx.x;
  const int w = tid >> 6, lane = tid & 63;
  const float* yr = y + (size_t)row * HD;
  const float* rr = res + (size_t)row * HD;

  float v0 = yr[tid] + rr[tid];
  float v1 = yr[tid + 256] + rr[tid + 256];

  __shared__ float red[4];
  float s = wave_sum(v0 + v1);
  if (lane == 0) red[w] = s;
  __syncthreads();
  const float mean = (red[0] + red[1] + red[2] + red[3]) * (1.f / HD);
  __syncthreads();

  const float d0 = v0 - mean, d1 = v1 - mean;
  float qv = wave_sum(d0 * d0 + d1 * d1);
  if (lane == 0) red[w] = qv;
  __syncthreads();
  const float var = (red[0] + red[1] + red[2] + red[3]) * (1.f / HD);
  const float rstd = rsqrtf(var + 1e-5f);

  out[(size_t)row * HD + tid] = d0 * rstd * g[tid] + bta[tid];
  out[(size_t)row * HD + tid + 256] = d1 * rstd * g[tid + 256] + bta[tid + 256];
}

// ---------------------------------------------------------------------------
extern "C" void kernel_launch(void* const* d_in, const int* in_sizes, int n_in,
                              void* d_out, int out_size, void* d_ws, size_t ws_size,
                              hipStream_t stream) {
  const int* idx = (const int*)d_in[0];
  const float* enc = (const float*)d_in[1];
  const unsigned char* emask = (const unsigned char*)d_in[2];
  // d_in[3] = tgt_len (compile-time TT)
  const float* emb = (const float*)d_in[4];
  const float* sa_wq = (const float*)d_in[5];
  const float* sa_bq = (const float*)d_in[6];
  const float* sa_wk = (const float*)d_in[7];
  const float* sa_bk = (const float*)d_in[8];
  const float* sa_wv = (const float*)d_in[9];
  const float* sa_bv = (const float*)d_in[10];
  const float* sa_wo = (const float*)d_in[11];
  const float* sa_bo = (const float*)d_in[12];
  const float* ln1g = (const float*)d_in[13];
  const float* ln1b = (const float*)d_in[14];
  const float* ea_wq = (const float*)d_in[15];
  const float* ea_bq = (const float*)d_in[16];
  const float* ea_wk = (const float*)d_in[17];
  const float* ea_bk = (const float*)d_in[18];
  const float* ea_wv = (const float*)d_in[19];
  const float* ea_bv = (const float*)d_in[20];
  const float* ea_wo = (const float*)d_in[21];
  const float* ea_bo = (const float*)d_in[22];
  const float* ln2g = (const float*)d_in[23];
  const float* ln2b = (const float*)d_in[24];
  const float* c1w = (const float*)d_in[25];
  const float* c1b = (const float*)d_in[26];
  const float* c2w = (const float*)d_in[27];
  const float* c2b = (const float*)d_in[28];
  const float* ln3g = (const float*)d_in[29];
  const float* ln3b = (const float*)d_in[30];

  const size_t MH = (size_t)MROWS * HD;  // 2,097,152 floats
  float* ws = (float*)d_ws;
  float* x  = ws;            // [4096,512]
  float* qb = ws + 1 * MH;   // [4096,512]  (also reused, together with kb, as FFN hidden [4096,1024])
  float* kb = ws + 2 * MH;
  float* vb = ws + 3 * MH;
  float* cx = ws + 4 * MH;
  float* yb = ws + 5 * MH;
  float* hb = qb;            // spans qb+kb regions: 4096*1024 floats

  const dim3 blk(256);
  const dim3 gemm512(MROWS / BM, HD / BN);    // (32, 8)
  const dim3 gemmFF(MROWS / BM, DFFN / BN);   // (32, 16)
  const dim3 attng(NB * NHD, TT / 64);        // (64, 8)

  embed_pe_kernel<<<MROWS, blk, 0, stream>>>(idx, emb, x);

  for (int l = 0; l < NL; ++l) {
    const size_t wo = (size_t)l * HD * HD;     // 512*512 weight slab
    const size_t bo512 = (size_t)l * HD;
    const size_t c1o = (size_t)l * HD * DFFN;
    const size_t c2o = (size_t)l * DFFN * HD;
    const size_t boFF = (size_t)l * DFFN;

    // ---- self attention ----
    gemm_kernel<<<gemm512, blk, 0, stream>>>(x, sa_wq + wo, sa_bq + bo512, qb, MROWS, HD, HD, 0);
    gemm_kernel<<<gemm512, blk, 0, stream>>>(x, sa_wk + wo, sa_bk + bo512, kb, MROWS, HD, HD, 0);
    gemm_kernel<<<gemm512, blk, 0, stream>>>(x, sa_wv + wo, sa_bv + bo512, vb, MROWS, HD, HD, 0);
    attn_kernel<<<attng, blk, 0, stream>>>(qb, kb, vb, cx, idx, emask, 1);
    gemm_kernel<<<gemm512, blk, 0, stream>>>(cx, sa_wo + wo, sa_bo + bo512, yb, MROWS, HD, HD, 0);
    ln_kernel<<<MROWS, blk, 0, stream>>>(yb, x, x, ln1g + bo512, ln1b + bo512);

    // ---- cross attention ----
    gemm_kernel<<<gemm512, blk, 0, stream>>>(x, ea_wq + wo, ea_bq + bo512, qb, MROWS, HD, HD, 0);
    gemm_kernel<<<gemm512, blk, 0, stream>>>(enc, ea_wk + wo, ea_bk + bo512, kb, MROWS, HD, HD, 0);
    gemm_kernel<<<gemm512, blk, 0, stream>>>(enc, ea_wv + wo, ea_bv + bo512, vb, MROWS, HD, HD, 0);
    attn_kernel<<<attng, blk, 0, stream>>>(qb, kb, vb, cx, idx, emask, 0);
    gemm_kernel<<<gemm512, blk, 0, stream>>>(cx, ea_wo + wo, ea_bo + bo512, yb, MROWS, HD, HD, 0);
    ln_kernel<<<MROWS, blk, 0, stream>>>(yb, x, x, ln2g + bo512, ln2b + bo512);

    // ---- FFN (conv1x1 == per-position linear) ----
    gemm_kernel<<<gemmFF, blk, 0, stream>>>(x, c1w + c1o, c1b + boFF, hb, MROWS, DFFN, HD, 1);
    gemm_kernel<<<gemm512, blk, 0, stream>>>(hb, c2w + c2o, c2b + bo512, yb, MROWS, HD, DFFN, 0);
    ln_kernel<<<MROWS, blk, 0, stream>>>(yb, x, x, ln3g + bo512, ln3b + bo512);
  }

  hipMemcpyAsync(d_out, x, MH * sizeof(float), hipMemcpyDeviceToDevice, stream);
}

// Round 2
// 2931.336 us; speedup vs baseline: 1.8893x; 1.8893x over previous
//
#include <hip/hip_runtime.h>
#include <hip/hip_bf16.h>
#include <math.h>

// Problem constants (reference shapes are fixed)
#define NL   6
#define HD   512
#define NHD  8
#define DK   64
#define DFFN 1024
#define NB   8
#define TT   512
#define MROWS (NB*TT)   // 4096

typedef __hip_bfloat16 bf16;
typedef __attribute__((ext_vector_type(8))) short short8v;
typedef __attribute__((ext_vector_type(4))) float f32x4;

__device__ __forceinline__ float wave_max(float v) {
#pragma unroll
  for (int off = 32; off; off >>= 1) v = fmaxf(v, __shfl_xor(v, off));
  return v;
}
__device__ __forceinline__ float wave_sum(float v) {
#pragma unroll
  for (int off = 32; off; off >>= 1) v += __shfl_xor(v, off);
  return v;
}
__device__ __forceinline__ unsigned short f2bf(float x) {
  __hip_bfloat16 h = __float2bfloat16(x);
  return *reinterpret_cast<unsigned short*>(&h);
}
__device__ __forceinline__ float bf2f(unsigned short u) {
  return __uint_as_float(((unsigned)u) << 16);
}

// ---------------------------------------------------------------------------
// Weight prep: f32 [L][Kd][Nd] -> bf16 [L][Nd][Kd] (transpose + convert)
// grid (Nd/32, Kd/32, L), block 256
__global__ __launch_bounds__(256)
void wprep_kernel(const float* __restrict__ W, bf16* __restrict__ Wt, int Kd, int Nd) {
  __shared__ float t[32][33];
  const size_t mo = (size_t)blockIdx.z * Kd * Nd;
  const int n0 = blockIdx.x * 32, k0 = blockIdx.y * 32;
  const int tx = threadIdx.x & 31, ty = threadIdx.x >> 5;  // 32 x 8
#pragma unroll
  for (int j = 0; j < 4; ++j)
    t[ty + j * 8][tx] = W[mo + (size_t)(k0 + ty + j * 8) * Nd + n0 + tx];
  __syncthreads();
#pragma unroll
  for (int j = 0; j < 4; ++j)
    Wt[mo + (size_t)(n0 + ty + j * 8) * Kd + k0 + tx] = __float2bfloat16(t[tx][ty + j * 8]);
}

// f32 -> bf16 elementwise, 4 per thread
__global__ __launch_bounds__(256)
void cvtbf16_kernel(const float* __restrict__ in, unsigned short* __restrict__ out) {
  const int i = (blockIdx.x * 256 + threadIdx.x) * 4;
  float4 v = *(const float4*)(in + i);
  out[i + 0] = f2bf(v.x); out[i + 1] = f2bf(v.y);
  out[i + 2] = f2bf(v.z); out[i + 3] = f2bf(v.w);
}

// ---------------------------------------------------------------------------
// Embedding + sinusoidal PE; writes f32 x and bf16 xb
__global__ __launch_bounds__(256)
void embed_pe_kernel(const int* __restrict__ idx, const float* __restrict__ emb,
                     float* __restrict__ x, unsigned short* __restrict__ xb) {
  const int row = blockIdx.x;
  const int t = row & (TT - 1);
  const int tok = idx[row];
  const float cdiv = -0.017988946009466842f;  // -ln(10000)/512
#pragma unroll
  for (int e0 = 0; e0 < 2; ++e0) {
    const int e = threadIdx.x + e0 * 256;
    const float div = __expf((float)(e & ~1) * cdiv);
    const float ang = (float)t * div;
    const float pe = (e & 1) ? cosf(ang) : sinf(ang);
    const float v = emb[(size_t)tok * HD + e] + pe;
    x[(size_t)row * HD + e] = v;
    xb[(size_t)row * HD + e] = f2bf(v);
  }
}

// ---------------------------------------------------------------------------
// bf16 MFMA GEMM: C[M,N] = A[M,K] @ Bt[N,K]^T + bias[N]
// 64x64 tile, BK=64, 256 threads (4 waves, each 32x32), 16x16x32 bf16 MFMA.
// LDS XOR-swizzle (byte ^= (row&7)<<4) on write and read -> conflict-free b128.
__device__ __forceinline__ void gemm_compute(const char* As, const char* Bs,
                                             int wm, int wn, int lane,
                                             f32x4 (&acc)[2][2]) {
  const int rsw = (lane & 7) << 4;
  const int csel = (lane >> 4) * 16;
  short8v af[2][2], bfr[2][2];
#pragma unroll
  for (int m = 0; m < 2; ++m)
#pragma unroll
    for (int kk = 0; kk < 2; ++kk) {
      const int row = wm * 32 + m * 16 + (lane & 15);
      af[m][kk] = *(const short8v*)(As + row * 128 + ((kk * 64 + csel) ^ rsw));
    }
#pragma unroll
  for (int n = 0; n < 2; ++n)
#pragma unroll
    for (int kk = 0; kk < 2; ++kk) {
      const int row = wn * 32 + n * 16 + (lane & 15);
      bfr[n][kk] = *(const short8v*)(Bs + row * 128 + ((kk * 64 + csel) ^ rsw));
    }
#pragma unroll
  for (int m = 0; m < 2; ++m)
#pragma unroll
    for (int n = 0; n < 2; ++n) {
      acc[m][n] = __builtin_amdgcn_mfma_f32_16x16x32_bf16(af[m][0], bfr[n][0], acc[m][n], 0, 0, 0);
      acc[m][n] = __builtin_amdgcn_mfma_f32_16x16x32_bf16(af[m][1], bfr[n][1], acc[m][n], 0, 0, 0);
    }
}

template<int OUT_BF16, int RELU>
__global__ __launch_bounds__(256)
void mgemm_kernel(const bf16* __restrict__ A, const bf16* __restrict__ Bt,
                  const float* __restrict__ bias, float* __restrict__ Cf,
                  unsigned short* __restrict__ Cb, int M, int N, int K) {
  __shared__ __attribute__((aligned(16))) char As[64 * 128];
  __shared__ __attribute__((aligned(16))) char Bs[64 * 128];

  const int tid = threadIdx.x;
  const int w = tid >> 6, lane = tid & 63;
  const int wm = w >> 1, wn = w & 1;
  const int m0 = blockIdx.x * 64, n0 = blockIdx.y * 64;

  // staging: wave w owns rows w*16 + j*8 + (lane>>3), j = 0,1 (for both tiles)
  const int sr = w * 16 + (lane >> 3);
  const int scol = (lane & 7) * 16;            // byte col within 128B k-row
  const int swc = scol ^ ((sr & 7) << 4);      // swizzled LDS byte col (same for sr and sr+8)
  const bf16* ga0 = A + (size_t)(m0 + sr) * K + (scol >> 1);
  const bf16* ga1 = A + (size_t)(m0 + sr + 8) * K + (scol >> 1);
  const bf16* gb0 = Bt + (size_t)(n0 + sr) * K + (scol >> 1);
  const bf16* gb1 = Bt + (size_t)(n0 + sr + 8) * K + (scol >> 1);
  char* la0 = As + sr * 128 + swc;
  char* la1 = As + (sr + 8) * 128 + swc;
  char* lb0 = Bs + sr * 128 + swc;
  char* lb1 = Bs + (sr + 8) * 128 + swc;

  f32x4 acc[2][2] = {};

  short8v ra0 = *(const short8v*)ga0, ra1 = *(const short8v*)ga1;
  short8v rb0 = *(const short8v*)gb0, rb1 = *(const short8v*)gb1;
  short8v sa0, sa1, sb0, sb1;

  for (int k0 = 0; k0 < K; k0 += 128) {
    __syncthreads();
    *(short8v*)la0 = ra0; *(short8v*)la1 = ra1;
    *(short8v*)lb0 = rb0; *(short8v*)lb1 = rb1;
    __syncthreads();
    // issue next-half loads early (hide HBM latency under MFMA)
    sa0 = *(const short8v*)(ga0 + k0 + 64); sa1 = *(const short8v*)(ga1 + k0 + 64);
    sb0 = *(const short8v*)(gb0 + k0 + 64); sb1 = *(const short8v*)(gb1 + k0 + 64);
    gemm_compute(As, Bs, wm, wn, lane, acc);
    __syncthreads();
    *(short8v*)la0 = sa0; *(short8v*)la1 = sa1;
    *(short8v*)lb0 = sb0; *(short8v*)lb1 = sb1;
    __syncthreads();
    if (k0 + 128 < K) {
      ra0 = *(const short8v*)(ga0 + k0 + 128); ra1 = *(const short8v*)(ga1 + k0 + 128);
      rb0 = *(const short8v*)(gb0 + k0 + 128); rb1 = *(const short8v*)(gb1 + k0 + 128);
    }
    gemm_compute(As, Bs, wm, wn, lane, acc);
  }

  // epilogue: D row=(lane>>4)*4+r, col=lane&15 per 16x16 fragment
  const int crow = (lane >> 4) * 4;
  const int ccol = lane & 15;
#pragma unroll
  for (int m = 0; m < 2; ++m)
#pragma unroll
    for (int n = 0; n < 2; ++n) {
      const int gr = m0 + wm * 32 + m * 16 + crow;
      const int gc = n0 + wn * 32 + n * 16 + ccol;
      const float bs = bias[gc];
#pragma unroll
      for (int r = 0; r < 4; ++r) {
        float v = acc[m][n][r] + bs;
        if (RELU) v = fmaxf(v, 0.f);
        if (OUT_BF16) Cb[(size_t)(gr + r) * N + gc] = f2bf(v);
        else          Cf[(size_t)(gr + r) * N + gc] = v;
      }
    }
}

// ---------------------------------------------------------------------------
// Flash-style attention (f32 internals, bf16 I/O).
// grid = (B*NHD, TT/64), block = 256 (4 waves x 16 rows).
__global__ __launch_bounds__(256)
void attn_kernel(const unsigned short* __restrict__ q, const unsigned short* __restrict__ k,
                 const unsigned short* __restrict__ v, unsigned short* __restrict__ ctx,
                 const int* __restrict__ idx, const unsigned char* __restrict__ emask,
                 int causal) {
  __shared__ float qt[64][68];
  __shared__ float kt[64][68];
  __shared__ float vtT[64][68];
  __shared__ float pl[4][64];

  const int bh = blockIdx.x;
  const int b = bh >> 3;
  const int h = bh & 7;
  const int qbase = blockIdx.y * 64;
  const int tid = threadIdx.x;
  const int w = tid >> 6;
  const int lane = tid & 63;

  {
    const int r = tid >> 2;
    const int c0 = (tid & 3) * 16;
    const unsigned short* qp = q + (size_t)(b * TT + qbase + r) * HD + h * DK + c0;
#pragma unroll
    for (int j = 0; j < 2; ++j) {
      short8v u = *(const short8v*)(qp + j * 8);
#pragma unroll
      for (int e = 0; e < 8; ++e) qt[r][c0 + j * 8 + e] = bf2f((unsigned short)u[e]);
    }
  }

  float m[16], l[16], acc[16];
#pragma unroll
  for (int i = 0; i < 16; ++i) { m[i] = -1e30f; l[i] = 0.f; acc[i] = 0.f; }

  for (int kt0 = 0; kt0 < TT; kt0 += 64) {
    __syncthreads();
    {
      const int r = tid >> 2;
      const int c0 = (tid & 3) * 16;
      const unsigned short* kp = k + (size_t)(b * TT + kt0 + r) * HD + h * DK + c0;
      const unsigned short* vp = v + (size_t)(b * TT + kt0 + r) * HD + h * DK + c0;
#pragma unroll
      for (int j = 0; j < 2; ++j) {
        short8v uk = *(const short8v*)(kp + j * 8);
        short8v uv = *(const short8v*)(vp + j * 8);
#pragma unroll
        for (int e = 0; e < 8; ++e) {
          kt[r][c0 + j * 8 + e] = bf2f((unsigned short)uk[e]);
          vtT[c0 + j * 8 + e][r] = bf2f((unsigned short)uv[e]);
        }
      }
    }
    __syncthreads();

    const int kg = kt0 + lane;
    const bool keymask = causal ? (idx[b * TT + kg] == 0)
                                : (emask[b * TT + kg] != 0);

#pragma unroll 1
    for (int i = 0; i < 16; ++i) {
      const int r = w * 16 + i;
      const int qpos = qbase + r;
      float s = 0.f;
      const float4* qr = (const float4*)&qt[r][0];
      const float4* kr = (const float4*)&kt[lane][0];
#pragma unroll
      for (int j = 0; j < 16; ++j) {
        float4 a = qr[j], bb = kr[j];
        s += a.x * bb.x + a.y * bb.y + a.z * bb.z + a.w * bb.w;
      }
      s *= 0.125f;
      if (keymask || (causal && kg > qpos)) s = -1e9f;

      const float sm = wave_max(s);
      const float mn = fmaxf(m[i], sm);
      const float sc = __expf(m[i] - mn);
      const float p = __expf(s - mn);
      const float ps = wave_sum(p);
      m[i] = mn;
      l[i] = l[i] * sc + ps;
      pl[w][lane] = p;

      float a = acc[i] * sc;
      const float4* pr = (const float4*)&pl[w][0];
      const float4* vr = (const float4*)&vtT[lane][0];
#pragma unroll
      for (int j = 0; j < 16; ++j) {
        float4 pp = pr[j], vv = vr[j];
        a += pp.x * vv.x + pp.y * vv.y + pp.z * vv.z + pp.w * vv.w;
      }
      acc[i] = a;
    }
  }

#pragma unroll
  for (int i = 0; i < 16; ++i) {
    const int qpos = qbase + w * 16 + i;
    ctx[(size_t)(b * TT + qpos) * HD + h * DK + lane] = f2bf(acc[i] / l[i]);
  }
}

// ---------------------------------------------------------------------------
// Fused residual-add + LayerNorm; writes f32 out and bf16 outb. out may alias res.
__global__ __launch_bounds__(256)
void ln_kernel(const float* __restrict__ y, const float* __restrict__ res,
               float* __restrict__ out, unsigned short* __restrict__ outb,
               const float* __restrict__ g, const float* __restrict__ bta) {
  const int row = blockIdx.x;
  const int tid = threadIdx.x;
  const int w = tid >> 6, lane = tid & 63;
  const float* yr = y + (size_t)row * HD;
  const float* rr = res + (size_t)row * HD;

  float v0 = yr[tid] + rr[tid];
  float v1 = yr[tid + 256] + rr[tid + 256];

  __shared__ float red[4];
  float s = wave_sum(v0 + v1);
  if (lane == 0) red[w] = s;
  __syncthreads();
  const float mean = (red[0] + red[1] + red[2] + red[3]) * (1.f / HD);
  __syncthreads();

  const float d0 = v0 - mean, d1 = v1 - mean;
  float qv = wave_sum(d0 * d0 + d1 * d1);
  if (lane == 0) red[w] = qv;
  __syncthreads();
  const float var = (red[0] + red[1] + red[2] + red[3]) * (1.f / HD);
  const float rstd = rsqrtf(var + 1e-5f);

  const float o0 = d0 * rstd * g[tid] + bta[tid];
  const float o1 = d1 * rstd * g[tid + 256] + bta[tid + 256];
  out[(size_t)row * HD + tid] = o0;
  out[(size_t)row * HD + tid + 256] = o1;
  outb[(size_t)row * HD + tid] = f2bf(o0);
  outb[(size_t)row * HD + tid + 256] = f2bf(o1);
}

// ---------------------------------------------------------------------------
extern "C" void kernel_launch(void* const* d_in, const int* in_sizes, int n_in,
                              void* d_out, int out_size, void* d_ws, size_t ws_size,
                              hipStream_t stream) {
  const int* idx = (const int*)d_in[0];
  const float* enc = (const float*)d_in[1];
  const unsigned char* emask = (const unsigned char*)d_in[2];
  const float* emb = (const float*)d_in[4];
  const float* sa_wq = (const float*)d_in[5];
  const float* sa_bq = (const float*)d_in[6];
  const float* sa_wk = (const float*)d_in[7];
  const float* sa_bk = (const float*)d_in[8];
  const float* sa_wv = (const float*)d_in[9];
  const float* sa_bv = (const float*)d_in[10];
  const float* sa_wo = (const float*)d_in[11];
  const float* sa_bo = (const float*)d_in[12];
  const float* ln1g = (const float*)d_in[13];
  const float* ln1b = (const float*)d_in[14];
  const float* ea_wq = (const float*)d_in[15];
  const float* ea_bq = (const float*)d_in[16];
  const float* ea_wk = (const float*)d_in[17];
  const float* ea_bk = (const float*)d_in[18];
  const float* ea_wv = (const float*)d_in[19];
  const float* ea_bv = (const float*)d_in[20];
  const float* ea_wo = (const float*)d_in[21];
  const float* ea_bo = (const float*)d_in[22];
  const float* ln2g = (const float*)d_in[23];
  const float* ln2b = (const float*)d_in[24];
  const float* c1w = (const float*)d_in[25];
  const float* c1b = (const float*)d_in[26];
  const float* c2w = (const float*)d_in[27];
  const float* c2b = (const float*)d_in[28];
  const float* ln3g = (const float*)d_in[29];
  const float* ln3b = (const float*)d_in[30];

  const size_t MH = (size_t)MROWS * HD;       // 2,097,152
  const size_t SQ = (size_t)HD * HD;          // 262,144
  char* ws = (char*)d_ws;
  // layout (bytes from ws start):
  float*          x    = (float*)(ws + 0);                   // 8 MB f32
  unsigned short* xb   = (unsigned short*)(ws + (8u << 20)); // 4 MB bf16
  unsigned short* qb   = (unsigned short*)(ws + (12u << 20));// 4 MB bf16
  unsigned short* kb   = (unsigned short*)(ws + (16u << 20));// 4 MB bf16
  unsigned short* vb   = (unsigned short*)(ws + (20u << 20));// 4 MB bf16
  float*          yb   = (float*)(ws + (24u << 20));         // 8 MB f32
  unsigned short* cxb  = (unsigned short*)(ws + (32u << 20));// 4 MB bf16
  unsigned short* encb = (unsigned short*)(ws + (36u << 20));// 4 MB bf16
  bf16*           wt   = (bf16*)(ws + (40u << 20));          // 37.75 MB bf16
  unsigned short* hb   = qb;  // FFN hidden [4096,1024] bf16, aliases qb+kb (8 MB)

  bf16* t_sa_q = wt;
  bf16* t_sa_k = wt + 6 * SQ;
  bf16* t_sa_v = wt + 12 * SQ;
  bf16* t_sa_o = wt + 18 * SQ;
  bf16* t_ea_q = wt + 24 * SQ;
  bf16* t_ea_k = wt + 30 * SQ;
  bf16* t_ea_v = wt + 36 * SQ;
  bf16* t_ea_o = wt + 42 * SQ;
  bf16* t_c1   = wt + 48 * SQ;            // [6][1024][512]
  bf16* t_c2   = wt + 48 * SQ + 12 * SQ;  // [6][512][1024]

  const dim3 blk(256);
  const dim3 g512(MROWS / 64, HD / 64);   // (64, 8)
  const dim3 gFF(MROWS / 64, DFFN / 64);  // (64, 16)
  const dim3 attng(NB * NHD, TT / 64);

  // ---- weight prep (once per call) ----
  wprep_kernel<<<dim3(16, 16, NL), blk, 0, stream>>>(sa_wq, t_sa_q, HD, HD);
  wprep_kernel<<<dim3(16, 16, NL), blk, 0, stream>>>(sa_wk, t_sa_k, HD, HD);
  wprep_kernel<<<dim3(16, 16, NL), blk, 0, stream>>>(sa_wv, t_sa_v, HD, HD);
  wprep_kernel<<<dim3(16, 16, NL), blk, 0, stream>>>(sa_wo, t_sa_o, HD, HD);
  wprep_kernel<<<dim3(16, 16, NL), blk, 0, stream>>>(ea_wq, t_ea_q, HD, HD);
  wprep_kernel<<<dim3(16, 16, NL), blk, 0, stream>>>(ea_wk, t_ea_k, HD, HD);
  wprep_kernel<<<dim3(16, 16, NL), blk, 0, stream>>>(ea_wv, t_ea_v, HD, HD);
  wprep_kernel<<<dim3(16, 16, NL), blk, 0, stream>>>(ea_wo, t_ea_o, HD, HD);
  wprep_kernel<<<dim3(32, 16, NL), blk, 0, stream>>>(c1w, t_c1, HD, DFFN);
  wprep_kernel<<<dim3(16, 32, NL), blk, 0, stream>>>(c2w, t_c2, DFFN, HD);
  cvtbf16_kernel<<<MH / 1024, blk, 0, stream>>>(enc, encb);

  embed_pe_kernel<<<MROWS, blk, 0, stream>>>(idx, emb, x, xb);

  for (int l = 0; l < NL; ++l) {
    const size_t wo = (size_t)l * SQ;
    const size_t b512 = (size_t)l * HD;
    const size_t w1 = (size_t)l * HD * DFFN;
    const size_t bFF = (size_t)l * DFFN;

    // ---- self attention ----
    mgemm_kernel<1, 0><<<g512, blk, 0, stream>>>((const bf16*)xb, t_sa_q + wo, sa_bq + b512, nullptr, qb, MROWS, HD, HD);
    mgemm_kernel<1, 0><<<g512, blk, 0, stream>>>((const bf16*)xb, t_sa_k + wo, sa_bk + b512, nullptr, kb, MROWS, HD, HD);
    mgemm_kernel<1, 0><<<g512, blk, 0, stream>>>((const bf16*)xb, t_sa_v + wo, sa_bv + b512, nullptr, vb, MROWS, HD, HD);
    attn_kernel<<<attng, blk, 0, stream>>>(qb, kb, vb, cxb, idx, emask, 1);
    mgemm_kernel<0, 0><<<g512, blk, 0, stream>>>((const bf16*)cxb, t_sa_o + wo, sa_bo + b512, yb, nullptr, MROWS, HD, HD);
    ln_kernel<<<MROWS, blk, 0, stream>>>(yb, x, x, xb, ln1g + b512, ln1b + b512);

    // ---- cross attention ----
    mgemm_kernel<1, 0><<<g512, blk, 0, stream>>>((const bf16*)xb, t_ea_q + wo, ea_bq + b512, nullptr, qb, MROWS, HD, HD);
    mgemm_kernel<1, 0><<<g512, blk, 0, stream>>>((const bf16*)encb, t_ea_k + wo, ea_bk + b512, nullptr, kb, MROWS, HD, HD);
    mgemm_kernel<1, 0><<<g512, blk, 0, stream>>>((const bf16*)encb, t_ea_v + wo, ea_bv + b512, nullptr, vb, MROWS, HD, HD);
    attn_kernel<<<attng, blk, 0, stream>>>(qb, kb, vb, cxb, idx, emask, 0);
    mgemm_kernel<0, 0><<<g512, blk, 0, stream>>>((const bf16*)cxb, t_ea_o + wo, ea_bo + b512, yb, nullptr, MROWS, HD, HD);
    ln_kernel<<<MROWS, blk, 0, stream>>>(yb, x, x, xb, ln2g + b512, ln2b + b512);

    // ---- FFN ----
    mgemm_kernel<1, 1><<<gFF, blk, 0, stream>>>((const bf16*)xb, t_c1 + w1, c1b + bFF, nullptr, hb, MROWS, DFFN, HD);
    mgemm_kernel<0, 0><<<g512, blk, 0, stream>>>((const bf16*)hb, t_c2 + w1, c2b + b512, yb, nullptr, MROWS, HD, DFFN);
    ln_kernel<<<MROWS, blk, 0, stream>>>(yb, x, x, xb, ln3g + b512, ln3b + b512);
  }

  hipMemcpyAsync(d_out, x, MH * sizeof(float), hipMemcpyDeviceToDevice, stream);
}

// Round 3
// 926.849 us; speedup vs baseline: 5.9753x; 3.1627x over previous
//
#include <hip/hip_runtime.h>
#include <hip/hip_bf16.h>
#include <math.h>

// Problem constants (reference shapes are fixed)
#define NL   6
#define HD   512
#define NHD  8
#define DK   64
#define DFFN 1024
#define NB   8
#define TT   512
#define MROWS (NB*TT)   // 4096

typedef __hip_bfloat16 bf16;
typedef __attribute__((ext_vector_type(8))) short short8v;
typedef __attribute__((ext_vector_type(4))) float f32x4;

__device__ __forceinline__ float wave_sum(float v) {
#pragma unroll
  for (int off = 32; off; off >>= 1) v += __shfl_xor(v, off);
  return v;
}
__device__ __forceinline__ unsigned short f2bf(float x) {
  __hip_bfloat16 h = __float2bfloat16(x);
  return *reinterpret_cast<unsigned short*>(&h);
}

// ---------------------------------------------------------------------------
// Weight prep: f32 [L][Kd][Nd] -> bf16 [L][Nd][Kd] (transpose + convert)
__global__ __launch_bounds__(256)
void wprep_kernel(const float* __restrict__ W, bf16* __restrict__ Wt, int Kd, int Nd) {
  __shared__ float t[32][33];
  const size_t mo = (size_t)blockIdx.z * Kd * Nd;
  const int n0 = blockIdx.x * 32, k0 = blockIdx.y * 32;
  const int tx = threadIdx.x & 31, ty = threadIdx.x >> 5;
#pragma unroll
  for (int j = 0; j < 4; ++j)
    t[ty + j * 8][tx] = W[mo + (size_t)(k0 + ty + j * 8) * Nd + n0 + tx];
  __syncthreads();
#pragma unroll
  for (int j = 0; j < 4; ++j)
    Wt[mo + (size_t)(n0 + ty + j * 8) * Kd + k0 + tx] = __float2bfloat16(t[tx][ty + j * 8]);
}

// f32 -> bf16 elementwise, 4 per thread
__global__ __launch_bounds__(256)
void cvtbf16_kernel(const float* __restrict__ in, unsigned short* __restrict__ out) {
  const int i = (blockIdx.x * 256 + threadIdx.x) * 4;
  float4 v = *(const float4*)(in + i);
  out[i + 0] = f2bf(v.x); out[i + 1] = f2bf(v.y);
  out[i + 2] = f2bf(v.z); out[i + 3] = f2bf(v.w);
}

// ---------------------------------------------------------------------------
// Embedding + sinusoidal PE; writes f32 x and bf16 xb
__global__ __launch_bounds__(256)
void embed_pe_kernel(const int* __restrict__ idx, const float* __restrict__ emb,
                     float* __restrict__ x, unsigned short* __restrict__ xb) {
  const int row = blockIdx.x;
  const int t = row & (TT - 1);
  const int tok = idx[row];
  const float cdiv = -0.017988946009466842f;  // -ln(10000)/512
#pragma unroll
  for (int e0 = 0; e0 < 2; ++e0) {
    const int e = threadIdx.x + e0 * 256;
    const float div = __expf((float)(e & ~1) * cdiv);
    const float ang = (float)t * div;
    const float pe = (e & 1) ? cosf(ang) : sinf(ang);
    const float v = emb[(size_t)tok * HD + e] + pe;
    x[(size_t)row * HD + e] = v;
    xb[(size_t)row * HD + e] = f2bf(v);
  }
}

// ---------------------------------------------------------------------------
// bf16 MFMA GEMM: C[M,N] = A[M,K] @ Bt[N,K]^T + bias[N]
// 64x64 tile, BK=128 (two 64-halves), 256 threads (4 waves, each 32x32).
__device__ __forceinline__ void gemm_compute(const char* As, const char* Bs,
                                             int wm, int wn, int lane,
                                             f32x4 (&acc)[2][2]) {
  const int rsw = (lane & 7) << 4;
  const int csel = (lane >> 4) * 16;
  short8v af[2][2], bfr[2][2];
#pragma unroll
  for (int m = 0; m < 2; ++m)
#pragma unroll
    for (int kk = 0; kk < 2; ++kk) {
      const int row = wm * 32 + m * 16 + (lane & 15);
      af[m][kk] = *(const short8v*)(As + row * 128 + ((kk * 64 + csel) ^ rsw));
    }
#pragma unroll
  for (int n = 0; n < 2; ++n)
#pragma unroll
    for (int kk = 0; kk < 2; ++kk) {
      const int row = wn * 32 + n * 16 + (lane & 15);
      bfr[n][kk] = *(const short8v*)(Bs + row * 128 + ((kk * 64 + csel) ^ rsw));
    }
#pragma unroll
  for (int m = 0; m < 2; ++m)
#pragma unroll
    for (int n = 0; n < 2; ++n) {
      acc[m][n] = __builtin_amdgcn_mfma_f32_16x16x32_bf16(af[m][0], bfr[n][0], acc[m][n], 0, 0, 0);
      acc[m][n] = __builtin_amdgcn_mfma_f32_16x16x32_bf16(af[m][1], bfr[n][1], acc[m][n], 0, 0, 0);
    }
}

template<int OUT_BF16, int RELU>
__global__ __launch_bounds__(256)
void mgemm_kernel(const bf16* __restrict__ A, const bf16* __restrict__ Bt,
                  const float* __restrict__ bias, float* __restrict__ Cf,
                  unsigned short* __restrict__ Cb, int M, int N, int K) {
  __shared__ __attribute__((aligned(16))) char As[64 * 128];
  __shared__ __attribute__((aligned(16))) char Bs[64 * 128];

  const int tid = threadIdx.x;
  const int w = tid >> 6, lane = tid & 63;
  const int wm = w >> 1, wn = w & 1;
  const int m0 = blockIdx.x * 64, n0 = blockIdx.y * 64;

  const int sr = w * 16 + (lane >> 3);
  const int scol = (lane & 7) * 16;
  const int swc = scol ^ ((sr & 7) << 4);
  const bf16* ga0 = A + (size_t)(m0 + sr) * K + (scol >> 1);
  const bf16* ga1 = A + (size_t)(m0 + sr + 8) * K + (scol >> 1);
  const bf16* gb0 = Bt + (size_t)(n0 + sr) * K + (scol >> 1);
  const bf16* gb1 = Bt + (size_t)(n0 + sr + 8) * K + (scol >> 1);
  char* la0 = As + sr * 128 + swc;
  char* la1 = As + (sr + 8) * 128 + swc;
  char* lb0 = Bs + sr * 128 + swc;
  char* lb1 = Bs + (sr + 8) * 128 + swc;

  f32x4 acc[2][2] = {};

  short8v ra0 = *(const short8v*)ga0, ra1 = *(const short8v*)ga1;
  short8v rb0 = *(const short8v*)gb0, rb1 = *(const short8v*)gb1;
  short8v sa0, sa1, sb0, sb1;

  for (int k0 = 0; k0 < K; k0 += 128) {
    __syncthreads();
    *(short8v*)la0 = ra0; *(short8v*)la1 = ra1;
    *(short8v*)lb0 = rb0; *(short8v*)lb1 = rb1;
    __syncthreads();
    sa0 = *(const short8v*)(ga0 + k0 + 64); sa1 = *(const short8v*)(ga1 + k0 + 64);
    sb0 = *(const short8v*)(gb0 + k0 + 64); sb1 = *(const short8v*)(gb1 + k0 + 64);
    gemm_compute(As, Bs, wm, wn, lane, acc);
    __syncthreads();
    *(short8v*)la0 = sa0; *(short8v*)la1 = sa1;
    *(short8v*)lb0 = sb0; *(short8v*)lb1 = sb1;
    __syncthreads();
    if (k0 + 128 < K) {
      ra0 = *(const short8v*)(ga0 + k0 + 128); ra1 = *(const short8v*)(ga1 + k0 + 128);
      rb0 = *(const short8v*)(gb0 + k0 + 128); rb1 = *(const short8v*)(gb1 + k0 + 128);
    }
    gemm_compute(As, Bs, wm, wn, lane, acc);
  }

  const int crow = (lane >> 4) * 4;
  const int ccol = lane & 15;
#pragma unroll
  for (int m = 0; m < 2; ++m)
#pragma unroll
    for (int n = 0; n < 2; ++n) {
      const int gr = m0 + wm * 32 + m * 16 + crow;
      const int gc = n0 + wn * 32 + n * 16 + ccol;
      const float bs = bias[gc];
#pragma unroll
      for (int r = 0; r < 4; ++r) {
        float v = acc[m][n][r] + bs;
        if (RELU) v = fmaxf(v, 0.f);
        if (OUT_BF16) Cb[(size_t)(gr + r) * N + gc] = f2bf(v);
        else          Cf[(size_t)(gr + r) * N + gc] = v;
      }
    }
}

// ---------------------------------------------------------------------------
// MFMA flash attention. Block = (b,h,64 q-rows), 4 waves x 16 q-rows.
// S = QK^T via mfma (A=Q rows, B=K rows). Online softmax in D-frag layout.
// P -> per-wave swizzled LDS -> A-frag. V staged transposed [d][key] swizzled.
template<int CAUSAL>
__global__ __launch_bounds__(256)
void mattn_kernel(const unsigned short* __restrict__ q, const unsigned short* __restrict__ kgl,
                  const unsigned short* __restrict__ vgl, unsigned short* __restrict__ ctx,
                  const int* __restrict__ idx, const unsigned char* __restrict__ emask) {
  __shared__ __attribute__((aligned(16))) unsigned short kt[64 * 64];   // [key][d] swz
  __shared__ __attribute__((aligned(16))) unsigned short vt[64 * 64];   // [d][key] swz
  __shared__ __attribute__((aligned(16))) unsigned short pl[4][16 * 64];// per-wave P swz
  __shared__ float km[64];

  const int bh = blockIdx.x;
  const int b = bh >> 3, h = bh & 7;
  const int qbase = blockIdx.y * 64;
  const int tid = threadIdx.x, w = tid >> 6, lane = tid & 63;
  const int l4 = lane & 15, g = lane >> 4;

  // Q fragments held in registers: A row = q-row (w*16 + l4), k-chunk g*8 (+32)
  const unsigned short* qp = q + (size_t)(b * TT + qbase + w * 16 + l4) * HD + h * DK + g * 8;
  short8v aq0 = *(const short8v*)qp;
  short8v aq1 = *(const short8v*)(qp + 32);

  float m_r[4], l_r[4];
  f32x4 acc_o[4];
#pragma unroll
  for (int r = 0; r < 4; ++r) { m_r[r] = -1e30f; l_r[r] = 0.f; }
#pragma unroll
  for (int f = 0; f < 4; ++f) acc_o[f] = (f32x4){0.f, 0.f, 0.f, 0.f};

  const int kvEnd = CAUSAL ? (qbase + 64) : TT;
  for (int kt0 = 0; kt0 < kvEnd; kt0 += 64) {
    __syncthreads();
    // ---- stage mask flags ----
    if (tid < 64) {
      const int kp = b * TT + kt0 + tid;
      const bool mk = CAUSAL ? (idx[kp] == 0) : (emask[kp] != 0);
      km[tid] = mk ? 1.f : 0.f;
    }
    // ---- stage K rows [key][64] swizzled ----
    {
      const int r = tid >> 2;
      const int bc = (tid & 3) * 32;
      const unsigned short* kp = kgl + (size_t)(b * TT + kt0 + r) * HD + h * DK + (bc >> 1);
      short8v ka = *(const short8v*)kp;
      short8v kb2 = *(const short8v*)(kp + 8);
      const int sw = (r & 7) << 4;
      *(short8v*)((char*)kt + r * 128 + (bc ^ sw)) = ka;
      *(short8v*)((char*)kt + r * 128 + ((bc + 16) ^ sw)) = kb2;
    }
    // ---- stage V transposed [d][key] swizzled (paired-key b32 writes) ----
    {
      const int k2 = (tid & 31) * 2;
      const int d0 = (tid >> 5) * 8;
      const unsigned short* vp0 = vgl + (size_t)(b * TT + kt0 + k2) * HD + h * DK + d0;
      const unsigned short* vp1 = vp0 + HD;
      short8v v0 = *(const short8v*)vp0;
      short8v v1 = *(const short8v*)vp1;
#pragma unroll
      for (int j = 0; j < 8; ++j) {
        const int d = d0 + j;
        const unsigned pk = ((unsigned)(unsigned short)v0[j]) | (((unsigned)(unsigned short)v1[j]) << 16);
        *(unsigned*)((char*)vt + d * 128 + ((k2 * 2) ^ ((d & 7) << 4))) = pk;
      }
    }
    __syncthreads();

    // ---- QK^T ----
    f32x4 s4[4];
#pragma unroll
    for (int f = 0; f < 4; ++f) {
      const int krow = f * 16 + l4;
      const int sw = (krow & 7) << 4;
      short8v bk0 = *(const short8v*)((const char*)kt + krow * 128 + ((g * 16) ^ sw));
      short8v bk1 = *(const short8v*)((const char*)kt + krow * 128 + ((64 + g * 16) ^ sw));
      f32x4 a = {};
      a = __builtin_amdgcn_mfma_f32_16x16x32_bf16(aq0, bk0, a, 0, 0, 0);
      a = __builtin_amdgcn_mfma_f32_16x16x32_bf16(aq1, bk1, a, 0, 0, 0);
      s4[f] = a;
    }

    // ---- online softmax (rows = g*4 + r) ----
    float sc_r[4];
#pragma unroll
    for (int r = 0; r < 4; ++r) {
      const int qpos = qbase + w * 16 + g * 4 + r;
      float sf[4];
#pragma unroll
      for (int f = 0; f < 4; ++f) {
        const int kpos = kt0 + f * 16 + l4;
        float s = s4[f][r] * 0.125f;
        const bool msk = (km[f * 16 + l4] != 0.f) || (CAUSAL && kpos > qpos);
        sf[f] = msk ? -1e9f : s;
      }
      float mx = fmaxf(fmaxf(sf[0], sf[1]), fmaxf(sf[2], sf[3]));
#pragma unroll
      for (int off = 8; off; off >>= 1) mx = fmaxf(mx, __shfl_xor(mx, off));
      const float mn = fmaxf(m_r[r], mx);
      const float sc = __expf(m_r[r] - mn);
      m_r[r] = mn;
      sc_r[r] = sc;
      float ps = 0.f;
      const int prow = g * 4 + r;
      const int psw = (prow & 7) << 4;
#pragma unroll
      for (int f = 0; f < 4; ++f) {
        const float p = __expf(sf[f] - mn);
        ps += p;
        *(unsigned short*)((char*)pl[w] + prow * 128 + ((f * 32 + l4 * 2) ^ psw)) = f2bf(p);
      }
#pragma unroll
      for (int off = 8; off; off >>= 1) ps += __shfl_xor(ps, off);
      l_r[r] = l_r[r] * sc + ps;
    }

    // rescale O
#pragma unroll
    for (int f = 0; f < 4; ++f)
#pragma unroll
      for (int r = 0; r < 4; ++r) acc_o[f][r] *= sc_r[r];

    // ---- PV ----
    const int asw = (l4 & 7) << 4;
    short8v pa0 = *(const short8v*)((const char*)pl[w] + l4 * 128 + ((g * 16) ^ asw));
    short8v pa1 = *(const short8v*)((const char*)pl[w] + l4 * 128 + ((g * 16 + 64) ^ asw));
#pragma unroll
    for (int f = 0; f < 4; ++f) {
      const int drow = f * 16 + l4;
      const int sw = (drow & 7) << 4;
      short8v vb0 = *(const short8v*)((const char*)vt + drow * 128 + ((g * 16) ^ sw));
      short8v vb1 = *(const short8v*)((const char*)vt + drow * 128 + ((g * 16 + 64) ^ sw));
      acc_o[f] = __builtin_amdgcn_mfma_f32_16x16x32_bf16(pa0, vb0, acc_o[f], 0, 0, 0);
      acc_o[f] = __builtin_amdgcn_mfma_f32_16x16x32_bf16(pa1, vb1, acc_o[f], 0, 0, 0);
    }
  }

  // ---- epilogue ----
  float rl[4];
#pragma unroll
  for (int r = 0; r < 4; ++r) rl[r] = 1.f / l_r[r];
#pragma unroll
  for (int f = 0; f < 4; ++f)
#pragma unroll
    for (int r = 0; r < 4; ++r) {
      const int row = qbase + w * 16 + g * 4 + r;
      const int col = h * DK + f * 16 + l4;
      ctx[(size_t)(b * TT + row) * HD + col] = f2bf(acc_o[f][r] * rl[r]);
    }
}

// ---------------------------------------------------------------------------
// Fused residual-add + LayerNorm; writes f32 out and bf16 outb. out may alias res.
__global__ __launch_bounds__(256)
void ln_kernel(const float* __restrict__ y, const float* __restrict__ res,
               float* __restrict__ out, unsigned short* __restrict__ outb,
               const float* __restrict__ g, const float* __restrict__ bta) {
  const int row = blockIdx.x;
  const int tid = threadIdx.x;
  const int w = tid >> 6, lane = tid & 63;
  const float* yr = y + (size_t)row * HD;
  const float* rr = res + (size_t)row * HD;

  float v0 = yr[tid] + rr[tid];
  float v1 = yr[tid + 256] + rr[tid + 256];

  __shared__ float red[4];
  float s = wave_sum(v0 + v1);
  if (lane == 0) red[w] = s;
  __syncthreads();
  const float mean = (red[0] + red[1] + red[2] + red[3]) * (1.f / HD);
  __syncthreads();

  const float d0 = v0 - mean, d1 = v1 - mean;
  float qv = wave_sum(d0 * d0 + d1 * d1);
  if (lane == 0) red[w] = qv;
  __syncthreads();
  const float var = (red[0] + red[1] + red[2] + red[3]) * (1.f / HD);
  const float rstd = rsqrtf(var + 1e-5f);

  const float o0 = d0 * rstd * g[tid] + bta[tid];
  const float o1 = d1 * rstd * g[tid + 256] + bta[tid + 256];
  out[(size_t)row * HD + tid] = o0;
  out[(size_t)row * HD + tid + 256] = o1;
  outb[(size_t)row * HD + tid] = f2bf(o0);
  outb[(size_t)row * HD + tid + 256] = f2bf(o1);
}

// ---------------------------------------------------------------------------
extern "C" void kernel_launch(void* const* d_in, const int* in_sizes, int n_in,
                              void* d_out, int out_size, void* d_ws, size_t ws_size,
                              hipStream_t stream) {
  const int* idx = (const int*)d_in[0];
  const float* enc = (const float*)d_in[1];
  const unsigned char* emask = (const unsigned char*)d_in[2];
  const float* emb = (const float*)d_in[4];
  const float* sa_wq = (const float*)d_in[5];
  const float* sa_bq = (const float*)d_in[6];
  const float* sa_wk = (const float*)d_in[7];
  const float* sa_bk = (const float*)d_in[8];
  const float* sa_wv = (const float*)d_in[9];
  const float* sa_bv = (const float*)d_in[10];
  const float* sa_wo = (const float*)d_in[11];
  const float* sa_bo = (const float*)d_in[12];
  const float* ln1g = (const float*)d_in[13];
  const float* ln1b = (const float*)d_in[14];
  const float* ea_wq = (const float*)d_in[15];
  const float* ea_bq = (const float*)d_in[16];
  const float* ea_wk = (const float*)d_in[17];
  const float* ea_bk = (const float*)d_in[18];
  const float* ea_wv = (const float*)d_in[19];
  const float* ea_bv = (const float*)d_in[20];
  const float* ea_wo = (const float*)d_in[21];
  const float* ea_bo = (const float*)d_in[22];
  const float* ln2g = (const float*)d_in[23];
  const float* ln2b = (const float*)d_in[24];
  const float* c1w = (const float*)d_in[25];
  const float* c1b = (const float*)d_in[26];
  const float* c2w = (const float*)d_in[27];
  const float* c2b = (const float*)d_in[28];
  const float* ln3g = (const float*)d_in[29];
  const float* ln3b = (const float*)d_in[30];

  const size_t MH = (size_t)MROWS * HD;
  const size_t SQ = (size_t)HD * HD;
  char* ws = (char*)d_ws;
  float*          x    = (float*)(ws + 0);
  unsigned short* xb   = (unsigned short*)(ws + (8u << 20));
  unsigned short* qb   = (unsigned short*)(ws + (12u << 20));
  unsigned short* kb   = (unsigned short*)(ws + (16u << 20));
  unsigned short* vb   = (unsigned short*)(ws + (20u << 20));
  float*          yb   = (float*)(ws + (24u << 20));
  unsigned short* cxb  = (unsigned short*)(ws + (32u << 20));
  unsigned short* encb = (unsigned short*)(ws + (36u << 20));
  bf16*           wt   = (bf16*)(ws + (40u << 20));
  unsigned short* hb   = qb;  // FFN hidden aliases qb+kb

  bf16* t_sa_q = wt;
  bf16* t_sa_k = wt + 6 * SQ;
  bf16* t_sa_v = wt + 12 * SQ;
  bf16* t_sa_o = wt + 18 * SQ;
  bf16* t_ea_q = wt + 24 * SQ;
  bf16* t_ea_k = wt + 30 * SQ;
  bf16* t_ea_v = wt + 36 * SQ;
  bf16* t_ea_o = wt + 42 * SQ;
  bf16* t_c1   = wt + 48 * SQ;
  bf16* t_c2   = wt + 48 * SQ + 12 * SQ;

  const dim3 blk(256);
  const dim3 g512(MROWS / 64, HD / 64);
  const dim3 gFF(MROWS / 64, DFFN / 64);
  const dim3 attng(NB * NHD, TT / 64);

  wprep_kernel<<<dim3(16, 16, NL), blk, 0, stream>>>(sa_wq, t_sa_q, HD, HD);
  wprep_kernel<<<dim3(16, 16, NL), blk, 0, stream>>>(sa_wk, t_sa_k, HD, HD);
  wprep_kernel<<<dim3(16, 16, NL), blk, 0, stream>>>(sa_wv, t_sa_v, HD, HD);
  wprep_kernel<<<dim3(16, 16, NL), blk, 0, stream>>>(sa_wo, t_sa_o, HD, HD);
  wprep_kernel<<<dim3(16, 16, NL), blk, 0, stream>>>(ea_wq, t_ea_q, HD, HD);
  wprep_kernel<<<dim3(16, 16, NL), blk, 0, stream>>>(ea_wk, t_ea_k, HD, HD);
  wprep_kernel<<<dim3(16, 16, NL), blk, 0, stream>>>(ea_wv, t_ea_v, HD, HD);
  wprep_kernel<<<dim3(16, 16, NL), blk, 0, stream>>>(ea_wo, t_ea_o, HD, HD);
  wprep_kernel<<<dim3(32, 16, NL), blk, 0, stream>>>(c1w, t_c1, HD, DFFN);
  wprep_kernel<<<dim3(16, 32, NL), blk, 0, stream>>>(c2w, t_c2, DFFN, HD);
  cvtbf16_kernel<<<MH / 1024, blk, 0, stream>>>(enc, encb);

  embed_pe_kernel<<<MROWS, blk, 0, stream>>>(idx, emb, x, xb);

  for (int l = 0; l < NL; ++l) {
    const size_t wo = (size_t)l * SQ;
    const size_t b512 = (size_t)l * HD;
    const size_t w1 = (size_t)l * HD * DFFN;
    const size_t bFF = (size_t)l * DFFN;

    // ---- self attention ----
    mgemm_kernel<1, 0><<<g512, blk, 0, stream>>>((const bf16*)xb, t_sa_q + wo, sa_bq + b512, nullptr, qb, MROWS, HD, HD);
    mgemm_kernel<1, 0><<<g512, blk, 0, stream>>>((const bf16*)xb, t_sa_k + wo, sa_bk + b512, nullptr, kb, MROWS, HD, HD);
    mgemm_kernel<1, 0><<<g512, blk, 0, stream>>>((const bf16*)xb, t_sa_v + wo, sa_bv + b512, nullptr, vb, MROWS, HD, HD);
    mattn_kernel<1><<<attng, blk, 0, stream>>>(qb, kb, vb, cxb, idx, emask);
    mgemm_kernel<0, 0><<<g512, blk, 0, stream>>>((const bf16*)cxb, t_sa_o + wo, sa_bo + b512, yb, nullptr, MROWS, HD, HD);
    ln_kernel<<<MROWS, blk, 0, stream>>>(yb, x, x, xb, ln1g + b512, ln1b + b512);

    // ---- cross attention ----
    mgemm_kernel<1, 0><<<g512, blk, 0, stream>>>((const bf16*)xb, t_ea_q + wo, ea_bq + b512, nullptr, qb, MROWS, HD, HD);
    mgemm_kernel<1, 0><<<g512, blk, 0, stream>>>((const bf16*)encb, t_ea_k + wo, ea_bk + b512, nullptr, kb, MROWS, HD, HD);
    mgemm_kernel<1, 0><<<g512, blk, 0, stream>>>((const bf16*)encb, t_ea_v + wo, ea_bv + b512, nullptr, vb, MROWS, HD, HD);
    mattn_kernel<0><<<attng, blk, 0, stream>>>(qb, kb, vb, cxb, idx, emask);
    mgemm_kernel<0, 0><<<g512, blk, 0, stream>>>((const bf16*)cxb, t_ea_o + wo, ea_bo + b512, yb, nullptr, MROWS, HD, HD);
    ln_kernel<<<MROWS, blk, 0, stream>>>(yb, x, x, xb, ln2g + b512, ln2b + b512);

    // ---- FFN ----
    mgemm_kernel<1, 1><<<gFF, blk, 0, stream>>>((const bf16*)xb, t_c1 + w1, c1b + bFF, nullptr, hb, MROWS, DFFN, HD);
    mgemm_kernel<0, 0><<<g512, blk, 0, stream>>>((const bf16*)hb, t_c2 + w1, c2b + b512, yb, nullptr, MROWS, HD, DFFN);
    ln_kernel<<<MROWS, blk, 0, stream>>>(yb, x, x, xb, ln3g + b512, ln3b + b512);
  }

  hipMemcpyAsync(d_out, x, MH * sizeof(float), hipMemcpyDeviceToDevice, stream);
}